// Round 15
// baseline (421.872 us; speedup 1.0000x reference)
//
#include <hip/hip_runtime.h>

#define NN 20000
#define EE 320000
#define BB 64

typedef _Float16 half8 __attribute__((ext_vector_type(8)));
typedef float floatx4 __attribute__((ext_vector_type(4)));

// ---------------- prep: weight folding ----------------
__global__ void k_prep_edgeW(const float* __restrict__ edge_W, const float* __restrict__ edge_b,
                             const float* __restrict__ We0, const float* __restrict__ We1,
                             _Float16* __restrict__ Wpt0, _Float16* __restrict__ Wpt1) {
    __shared__ float row[256];
    int k = blockIdx.x, layer = blockIdx.y, j = threadIdx.x;
    row[j] = (k < 63) ? edge_W[k*256 + j] : edge_b[j];
    __syncthreads();
    const float* We = layer ? We1 : We0;
    float acc = 0.f;
    for (int t = 0; t < 256; ++t) acc += row[t] * We[t*256 + j];
    (layer ? Wpt1 : Wpt0)[j*64 + k] = (_Float16)acc;   // transposed [col][k] fp16
}

__global__ void k_prep_acat(const float* __restrict__ node_W, const float* __restrict__ node_b,
                            const float* __restrict__ Wl0, const float* __restrict__ bl0,
                            const float* __restrict__ Wr0, const float* __restrict__ br0,
                            float* __restrict__ Acat) {
    __shared__ float row[256];
    int k = blockIdx.x, j = threadIdx.x;
    if (j < 256) row[j] = (k < 5) ? node_W[k*256 + j] : node_b[j];
    __syncthreads();
    int jj = j & 255;
    const float* W = (j < 256) ? Wl0 : Wr0;
    float acc = 0.f;
    for (int t = 0; t < 256; ++t) acc += row[t] * W[t*256 + jj];
    if (k == 5) acc += (j < 256) ? bl0[jj] : br0[jj];
    Acat[k*512 + j] = acc;
}

__global__ void k_prep_t16(const float* __restrict__ Wl1, const float* __restrict__ bl1,
                           const float* __restrict__ Wr1, const float* __restrict__ br1,
                           const float* __restrict__ mlp_W,
                           _Float16* __restrict__ WlWr1t, float* __restrict__ blr1,
                           _Float16* __restrict__ mlpWt) {
    int n = blockIdx.x, k = threadIdx.x;
    if (n < 512) {
        float v = (n < 256) ? Wl1[k*256 + n] : Wr1[k*256 + (n - 256)];
        WlWr1t[n*256 + k] = (_Float16)v;
        if (k == 0) blr1[n] = (n < 256) ? bl1[n] : br1[n - 256];
    } else {
        int nn = n - 512;
        mlpWt[nn*256 + k] = (_Float16)mlp_W[k*64 + nn];
    }
}

// ---------------- streaming attr fp32->fp16 (+bias lane) with fused dst histogram ------
__global__ void k_conv_hist(const int* __restrict__ ei, const float* __restrict__ attr,
                            _Float16* __restrict__ attr16, int* __restrict__ counts) {
    int tid = threadIdx.x;
    int w = tid >> 6, lane = tid & 63;
    int e = blockIdx.x*4 + w;
    if (e >= EE) return;
    if (lane == 0) atomicAdd(&counts[ei[EE + e]], 1);
    float v = (lane < 63) ? attr[(size_t)e*63 + lane] : 1.0f;
    attr16[(size_t)e*64 + lane] = (_Float16)v;   // coalesced streaming write
}

__global__ __launch_bounds__(1024) void k_scan(const int* __restrict__ counts,
                                               int* __restrict__ row_ptr, int* __restrict__ cursor) {
    __shared__ int part[1024];
    int t = threadIdx.x;
    const int per = (NN + 1023) / 1024;
    int b0 = t*per, b1 = min(b0 + per, NN);
    int s = 0;
    for (int i = b0; i < b1; ++i) s += counts[i];
    part[t] = s; __syncthreads();
    for (int d = 1; d < 1024; d <<= 1) {
        int v = (t >= d) ? part[t-d] : 0;
        __syncthreads();
        part[t] += v;
        __syncthreads();
    }
    int run = (t == 0) ? 0 : part[t-1];
    for (int i = b0; i < b1; ++i) { row_ptr[i] = run; cursor[i] = run; run += counts[i]; }
    if (t == 0) row_ptr[NN] = EE;
}

// slim scatter: one packed {src, e} 8B random write per edge
__global__ void k_scatter(const int* __restrict__ ei, int* __restrict__ cursor,
                          int2* __restrict__ pair) {
    int e = blockIdx.x*256 + threadIdx.x;
    if (e < EE) {
        int d = ei[EE + e];
        int p = atomicAdd(&cursor[d], 1);
        pair[p] = make_int2(ei[e], e);
    }
}

// ---------------- layer 0 xl/xr via folded K=5 (fp16 out) ----------------
__global__ void k_xlxr0(const float* __restrict__ x, const float* __restrict__ Acat,
                        _Float16* __restrict__ xlxr16) {
    int n = blockIdx.x, j = threadIdx.x;
    float a0 = Acat[5*512 + j], a1 = Acat[5*512 + 256 + j];
#pragma unroll
    for (int k = 0; k < 5; ++k) {
        float xv = x[n*5 + k];
        a0 += xv * Acat[k*512 + j];
        a1 += xv * Acat[k*512 + 256 + j];
    }
    xlxr16[(size_t)n*512 + j] = (_Float16)a0;
    xlxr16[(size_t)n*512 + 256 + j] = (_Float16)a1;
}

// ---------------- fused GATv2 layer: cross-lane PV partials (low DS-op count) ----------
// 4 waves/block; wave w = head w. Depth-1 prefetch, Wpt B-fragments reloaded per tile (L1).
// alpha-phase x reads are kept in registers and reused for PV via xor-reduce + lane select.
#define NPB 4

#define LOADT() { \
    int er = tl + srow; if (er >= el) er = el - 1; \
    const _Float16* sp = &xlxr16[(size_t)pairp[er].x*512 + wave*64 + scol]; \
    rx0 = *(const half8*)&sp[0]; \
    rx1 = *(const half8*)&sp[8]; \
    int arow = tl + l15; if (arow >= el) arow = el - 1; \
    const _Float16* ap = &attr16[(size_t)pairp[arow].y*64]; \
    ra0 = *(const half8*)&ap[l4*8]; \
    ra1 = *(const half8*)&ap[32 + l4*8]; \
    rxr = (float)xlxr16[(size_t)nl*512 + 256 + wave*64 + lane]; \
}

__global__ __launch_bounds__(256) void k_fused(const _Float16* __restrict__ attr16,
        const int2* __restrict__ pairp, const int* __restrict__ row_ptr,
        const _Float16* __restrict__ Wpt, const float* __restrict__ att,
        const _Float16* __restrict__ xlxr16, _Float16* __restrict__ gat16,
        float* __restrict__ stats) {
    int tid = threadIdx.x;
    int wave = tid >> 6, lane = tid & 63;
    int l15 = lane & 15, l4 = lane >> 4;
    int srow = lane >> 2, scol = (lane & 3) * 16;

    __shared__ __align__(16) _Float16 xls[4][16][72];   // wave-private single buffer

    // per-lane Wpt fragment base (fragments reloaded per tile from L1-resident 32KB table)
    const _Float16* bp = Wpt + (size_t)(wave*64 + l15)*64 + l4*8;
    float attv[4];
#pragma unroll
    for (int ct = 0; ct < 4; ++ct) attv[ct] = att[wave*64 + ct*16 + l15];

    int n0 = blockIdx.x*NPB;
    int nEnd = n0 + NPB; if (nEnd > NN) nEnd = NN;

    // zero-fill empty nodes; find first nonempty
    int nc = -1, tc = 0, ec = 0;
    for (int m = n0; m < nEnd; ++m) {
        int s = row_ptr[m], e = row_ptr[m+1];
        if (e <= s) gat16[(size_t)m*256 + wave*64 + lane] = (_Float16)0.f;
        else if (nc < 0) { nc = m; tc = s; ec = e; }
    }
    if (nc < 0) return;

    int nl = nc, tl = tc, el = ec;
    auto advIt = [&](int& n, int& t, int& e) -> bool {
        t += 16;
        if (t < e) return true;
        for (;;) {
            ++n;
            if (n >= nEnd) return false;
            int s = row_ptr[n]; e = row_ptr[n+1];
            if (e > s) { t = s; return true; }
        }
    };

    half8 rx0, rx1, ra0, ra1;
    float rxr;
    LOADT();
    bool haveL = advIt(nl, tl, el);

    float m_run = -3.0e38f, l_run = 0.f, out_acc = 0.f;
    float sAcc = 0.f, qAcc = 0.f;
    for (;;) {
        int nt = ec - tc; if (nt > 16) nt = 16;
        // stage current tile
        *(half8*)&xls[wave][srow][scol]     = rx0;
        *(half8*)&xls[wave][srow][scol + 8] = rx1;
        // MFMA with per-tile B-fragment reload (L1 hit)
        floatx4 acc[4];
#pragma unroll
        for (int ct = 0; ct < 4; ++ct) {
            half8 b0 = *(const half8*)(bp + ct*1024);
            half8 b1 = *(const half8*)(bp + ct*1024 + 32);
            floatx4 z = {};
            acc[ct] = __builtin_amdgcn_mfma_f32_16x16x32_f16(ra0, b0, z, 0, 0, 0);
            acc[ct] = __builtin_amdgcn_mfma_f32_16x16x32_f16(ra1, b1, acc[ct], 0, 0, 0);
        }
        // xr fragment via shuffle
        float xrf[4];
#pragma unroll
        for (int ct = 0; ct < 4; ++ct) xrf[ct] = __shfl(rxr, ct*16 + l15);
        // prefetch next tile (regs free after MFMA/shfl issue)
        if (haveL) { LOADT(); haveL = advIt(nl, tl, el); }
        // alpha combine; x values kept in regs for PV partials (named, static indexing)
        float xv0[4], xv1[4], xv2[4], xv3[4];
        float p[4];
#pragma unroll
        for (int r = 0; r < 4; ++r) {
            int eidx = l4*4 + r;
            float x0 = (float)xls[wave][eidx][0*16 + l15];
            float x1 = (float)xls[wave][eidx][1*16 + l15];
            float x2 = (float)xls[wave][eidx][2*16 + l15];
            float x3 = (float)xls[wave][eidx][3*16 + l15];
            xv0[r] = x0; xv1[r] = x1; xv2[r] = x2; xv3[r] = x3;
            float m0 = acc[0][r] + x0 + xrf[0];
            float m1 = acc[1][r] + x1 + xrf[1];
            float m2 = acc[2][r] + x2 + xrf[2];
            float m3 = acc[3][r] + x3 + xrf[3];
            float pv = fmaxf(m0, 0.2f*m0) * attv[0]
                     + fmaxf(m1, 0.2f*m1) * attv[1]
                     + fmaxf(m2, 0.2f*m2) * attv[2]
                     + fmaxf(m3, 0.2f*m3) * attv[3];
            pv += __shfl_xor(pv, 1);
            pv += __shfl_xor(pv, 2);
            pv += __shfl_xor(pv, 4);
            pv += __shfl_xor(pv, 8);
            p[r] = (eidx < nt) ? pv : -3.0e38f;
        }
        // tile max: intra-lane over group's 4 edges, then cross-group
        float mt = fmaxf(fmaxf(p[0], p[1]), fmaxf(p[2], p[3]));
        mt = fmaxf(mt, __shfl_xor(mt, 16));
        mt = fmaxf(mt, __shfl_xor(mt, 32));
        float mnew = fmaxf(m_run, mt);
        float scale = __expf(m_run - mnew);
        out_acc *= scale; l_run *= scale;
        // 4 exps per lane (group-local), cross-group sum for denom
        float w4[4]; float wsum = 0.f;
#pragma unroll
        for (int r = 0; r < 4; ++r) { w4[r] = __expf(p[r] - mnew); wsum += w4[r]; }
        wsum += __shfl_xor(wsum, 16);
        wsum += __shfl_xor(wsum, 32);
        l_run += wsum;
        // PV partials: s_ct = sum over this group's 4 edges of w*x[edge][ct*16+l15];
        // xor-reduce over the 4 lane groups -> full sum over 16 edges; lane picks ct = l4.
        float s0 = w4[0]*xv0[0] + w4[1]*xv0[1] + w4[2]*xv0[2] + w4[3]*xv0[3];
        float s1 = w4[0]*xv1[0] + w4[1]*xv1[1] + w4[2]*xv1[2] + w4[3]*xv1[3];
        float s2 = w4[0]*xv2[0] + w4[1]*xv2[1] + w4[2]*xv2[2] + w4[3]*xv2[3];
        float s3 = w4[0]*xv3[0] + w4[1]*xv3[1] + w4[2]*xv3[2] + w4[3]*xv3[3];
        s0 += __shfl_xor(s0, 16); s0 += __shfl_xor(s0, 32);
        s1 += __shfl_xor(s1, 16); s1 += __shfl_xor(s1, 32);
        s2 += __shfl_xor(s2, 16); s2 += __shfl_xor(s2, 32);
        s3 += __shfl_xor(s3, 16); s3 += __shfl_xor(s3, 32);
        out_acc += (l4 == 0) ? s0 : (l4 == 1) ? s1 : (l4 == 2) ? s2 : s3;
        m_run = mnew;
        if (tc + 16 >= ec) {
            _Float16 h = (_Float16)(out_acc / l_run);
            gat16[(size_t)nc*256 + wave*64 + lane] = h;
            float hv = (float)h;
            sAcc += hv; qAcc += hv*hv;
            m_run = -3.0e38f; l_run = 0.f; out_acc = 0.f;
        }
        if (!advIt(nc, tc, ec)) break;
    }
    // fused BN stats: 16-sharded per-col partial sums
    int shard = blockIdx.x & 15;
    atomicAdd(&stats[shard*512 + wave*64 + lane], sAcc);
    atomicAdd(&stats[shard*512 + 256 + wave*64 + lane], qAcc);
}

__global__ void k_bn_final(const float* __restrict__ stats, const float* __restrict__ gamma,
                           const float* __restrict__ beta, float* __restrict__ ss) {
    int j = threadIdx.x;
    float s = 0.f, q = 0.f;
#pragma unroll
    for (int sh = 0; sh < 16; ++sh) {
        s += stats[sh*512 + j];
        q += stats[sh*512 + 256 + j];
    }
    float mean = s * (1.0f/NN);
    float var  = q * (1.0f/NN) - mean*mean;
    float sc = rsqrtf(var + 1e-5f) * gamma[j];
    ss[j] = sc;
    ss[256 + j] = beta[j] - mean*sc;
}

// ---------------- fp16 MFMA GEMM with fused BN+ReLU on A ----------------
template<bool RELU, typename OT>
__global__ __launch_bounds__(256) void k_gemm(const _Float16* __restrict__ A,
                       const float* __restrict__ ssv,
                       const _Float16* __restrict__ Bt,
                       const float* __restrict__ bias, OT* __restrict__ C,
                       int M, int ldc) {
    __shared__ __align__(16) _Float16 As[128][72];
    __shared__ __align__(16) _Float16 Bs[64][72];
    int tid = threadIdx.x;
    int wave = tid >> 6, lane = tid & 63;
    int l15 = lane & 15, l4 = lane >> 4;
    int row0 = blockIdx.x*128, n0 = blockIdx.y*64;
    floatx4 acc[2][4] = {};
    for (int k0 = 0; k0 < 256; k0 += 64) {
#pragma unroll
        for (int q = 0; q < 4; ++q) {
            int c = tid + q*256;
            int r = c >> 3, kc = (c & 7)*8;
            int gr = row0 + r; if (gr >= M) gr = M - 1;
            half8 g = *(const half8*)&A[(size_t)gr*256 + k0 + kc];
            _Float16 tmp[8];
#pragma unroll
            for (int i = 0; i < 8; ++i) {
                int colk = k0 + kc + i;
                float v = (float)g[i]*ssv[colk] + ssv[256 + colk];
                tmp[i] = (_Float16)fmaxf(v, 0.f);
            }
            *(half8*)&As[r][kc] = *(half8*)tmp;
        }
#pragma unroll
        for (int q = 0; q < 2; ++q) {
            int c = tid + q*256;
            int r = c >> 3, kc = (c & 7)*8;
            *(half8*)&Bs[r][kc] = *(const half8*)&Bt[(size_t)(n0 + r)*256 + k0 + kc];
        }
        __syncthreads();
#pragma unroll
        for (int ks = 0; ks < 64; ks += 32) {
            half8 a0 = *(const half8*)&As[wave*32 + l15][ks + l4*8];
            half8 a1 = *(const half8*)&As[wave*32 + 16 + l15][ks + l4*8];
#pragma unroll
            for (int nb = 0; nb < 4; ++nb) {
                half8 b = *(const half8*)&Bs[nb*16 + l15][ks + l4*8];
                acc[0][nb] = __builtin_amdgcn_mfma_f32_16x16x32_f16(a0, b, acc[0][nb], 0, 0, 0);
                acc[1][nb] = __builtin_amdgcn_mfma_f32_16x16x32_f16(a1, b, acc[1][nb], 0, 0, 0);
            }
        }
        __syncthreads();
    }
#pragma unroll
    for (int m = 0; m < 2; ++m)
#pragma unroll
    for (int nb = 0; nb < 4; ++nb) {
        int col = n0 + nb*16 + l15;
        float bv = bias[col];
#pragma unroll
        for (int r = 0; r < 4; ++r) {
            int grow = row0 + wave*32 + m*16 + l4*4 + r;
            if (grow < M) {
                float v = acc[m][nb][r] + bv;
                if (RELU) v = fmaxf(v, 0.f);
                C[(size_t)grow*ldc + col] = (OT)v;
            }
        }
    }
}

// ---------------- pooling (batch sorted -> contiguous ranges, no atomics) ----------------
__global__ void k_pool2(const float* __restrict__ mo, const int* __restrict__ batch,
                        float* __restrict__ pooledDiv) {
    int b = blockIdx.x;
    int j = threadIdx.x & 63, rg = threadIdx.x >> 6;
    int lo = 0, hi = NN;
    while (lo < hi) { int mid = (lo + hi) >> 1; if (batch[mid] < b) lo = mid + 1; else hi = mid; }
    int s = lo;
    lo = 0; hi = NN;
    while (lo < hi) { int mid = (lo + hi) >> 1; if (batch[mid] < b + 1) lo = mid + 1; else hi = mid; }
    int e = lo;
    float acc = 0.f;
    for (int r = s + rg; r < e; r += 4) acc += mo[(size_t)r*64 + j];
    __shared__ float red[256];
    red[threadIdx.x] = acc;
    __syncthreads();
    if (rg == 0) {
        float v = red[j] + red[64 + j] + red[128 + j] + red[192 + j];
        pooledDiv[b*64 + j] = v / fmaxf((float)(e - s), 1.f);
    }
}

__global__ void k_final(const float* __restrict__ pooledDiv,
                        const float* __restrict__ outW, const float* __restrict__ outb,
                        float* __restrict__ out) {
    int t = threadIdx.x;
    if (t >= 320) return;
    int b = t / 5, c = t % 5;
    float acc = outb[c];
    for (int k = 0; k < 64; ++k) acc += pooledDiv[b*64 + k] * outW[k*5 + c];
    out[t] = acc;
}

extern "C" void kernel_launch(void* const* d_in, const int* in_sizes, int n_in,
                              void* d_out, int out_size, void* d_ws, size_t ws_size,
                              hipStream_t stream) {
    const float* x      = (const float*)d_in[0];
    const int*   ei     = (const int*)d_in[1];
    const float* attr   = (const float*)d_in[2];
    const int*   batch  = (const int*)d_in[3];
    const float* node_W = (const float*)d_in[4];
    const float* node_b = (const float*)d_in[5];
    const float* edge_W = (const float*)d_in[6];
    const float* edge_b = (const float*)d_in[7];
    const float* Wl[2]   = {(const float*)d_in[8],  (const float*)d_in[17]};
    const float* bl[2]   = {(const float*)d_in[9],  (const float*)d_in[18]};
    const float* Wr[2]   = {(const float*)d_in[10], (const float*)d_in[19]};
    const float* br[2]   = {(const float*)d_in[11], (const float*)d_in[20]};
    const float* We[2]   = {(const float*)d_in[12], (const float*)d_in[21]};
    const float* att[2]  = {(const float*)d_in[13], (const float*)d_in[22]};
    const float* gamma[2]= {(const float*)d_in[15], (const float*)d_in[24]};
    const float* beta[2] = {(const float*)d_in[16], (const float*)d_in[25]};
    const float* mlp_W = (const float*)d_in[26];
    const float* mlp_b = (const float*)d_in[27];
    const float* out_W = (const float*)d_in[28];
    const float* out_b = (const float*)d_in[29];
    float* out = (float*)d_out;

    char* p = (char*)d_ws;
    size_t off = 0;
    auto carve = [&](size_t bytes) -> void* {
        void* r = p + off;
        off = (off + bytes + 255) & ~(size_t)255;
        return r;
    };
    _Float16* Wpt0   = (_Float16*)carve(256*64*2);
    _Float16* Wpt1   = (_Float16*)carve(256*64*2);
    float*    Acat   = (float*)carve(6*512*4);
    _Float16* WlWr1t = (_Float16*)carve(512*256*2);
    float*    blr1   = (float*)carve(512*4);
    _Float16* mlpWt  = (_Float16*)carve(64*256*2);
    float*    ss     = (float*)carve(512*4);
    _Float16* xlxr16 = (_Float16*)carve((size_t)NN*512*2);
    _Float16* gat16  = (_Float16*)carve((size_t)NN*256*2);
    float*    mlo    = (float*)carve((size_t)NN*64*4);
    _Float16* attr16 = (_Float16*)carve((size_t)EE*64*2);
    int*      row_ptr= (int*)carve((NN+1)*4);
    int2*     pairA  = (int2*)carve((size_t)EE*8);
    int*      cursor = (int*)carve(NN*4);
    float*    pooledDiv = (float*)carve(BB*64*4);
    char*     zz     = (char*)carve((NN + 2*16*512)*4);
    int*      counts = (int*)zz;
    float*    stats  = (float*)(zz + (size_t)NN*4);   // 2 layers x 16 shards x 512
    if (off > ws_size) return;  // workspace too small: bail

    hipMemsetAsync(zz, 0, (size_t)(NN + 2*16*512)*4, stream);
    k_prep_edgeW<<<dim3(64,2), 256, 0, stream>>>(edge_W, edge_b, We[0], We[1], Wpt0, Wpt1);
    k_prep_acat<<<6, 512, 0, stream>>>(node_W, node_b, Wl[0], bl[0], Wr[0], br[0], Acat);
    k_prep_t16<<<576, 256, 0, stream>>>(Wl[1], bl[1], Wr[1], br[1], mlp_W, WlWr1t, blr1, mlpWt);
    k_conv_hist<<<EE/4, 256, 0, stream>>>(ei, attr, attr16, counts);
    k_scan<<<1, 1024, 0, stream>>>(counts, row_ptr, cursor);
    k_scatter<<<(EE+255)/256, 256, 0, stream>>>(ei, cursor, pairA);
    k_xlxr0<<<NN, 256, 0, stream>>>(x, Acat, xlxr16);

    for (int L = 0; L < 2; ++L) {
        k_fused<<<(NN + NPB - 1)/NPB, 256, 0, stream>>>(attr16, pairA, row_ptr,
                 L ? Wpt1 : Wpt0, att[L], xlxr16, gat16, stats + L*8192);
        k_bn_final<<<1, 256, 0, stream>>>(stats + L*8192, gamma[L], beta[L], ss);
        if (L == 0)
            k_gemm<false, _Float16><<<dim3(157, 8), 256, 0, stream>>>(gat16, ss, WlWr1t, blr1, xlxr16, NN, 512);
        else
            k_gemm<true, float><<<dim3(157, 1), 256, 0, stream>>>(gat16, ss, mlpWt, mlp_b, mlo, NN, 64);
    }
    k_pool2<<<BB, 256, 0, stream>>>(mlo, batch, pooledDiv);
    k_final<<<1, 320, 0, stream>>>(pooledDiv, out_W, out_b, out);
}

// Round 16
// 418.935 us; speedup vs baseline: 1.0070x; 1.0070x over previous
//
#include <hip/hip_runtime.h>

#define NN 20000
#define EE 320000
#define BB 64

typedef _Float16 half8 __attribute__((ext_vector_type(8)));
typedef float floatx4 __attribute__((ext_vector_type(4)));

// ---------------- prep: weight folding ----------------
__global__ void k_prep_edgeW(const float* __restrict__ edge_W, const float* __restrict__ edge_b,
                             const float* __restrict__ We0, const float* __restrict__ We1,
                             _Float16* __restrict__ Wpt0, _Float16* __restrict__ Wpt1) {
    __shared__ float row[256];
    int k = blockIdx.x, layer = blockIdx.y, j = threadIdx.x;
    row[j] = (k < 63) ? edge_W[k*256 + j] : edge_b[j];
    __syncthreads();
    const float* We = layer ? We1 : We0;
    float acc = 0.f;
    for (int t = 0; t < 256; ++t) acc += row[t] * We[t*256 + j];
    (layer ? Wpt1 : Wpt0)[j*64 + k] = (_Float16)acc;   // transposed [col][k] fp16
}

__global__ void k_prep_acat(const float* __restrict__ node_W, const float* __restrict__ node_b,
                            const float* __restrict__ Wl0, const float* __restrict__ bl0,
                            const float* __restrict__ Wr0, const float* __restrict__ br0,
                            float* __restrict__ Acat) {
    __shared__ float row[256];
    int k = blockIdx.x, j = threadIdx.x;
    if (j < 256) row[j] = (k < 5) ? node_W[k*256 + j] : node_b[j];
    __syncthreads();
    int jj = j & 255;
    const float* W = (j < 256) ? Wl0 : Wr0;
    float acc = 0.f;
    for (int t = 0; t < 256; ++t) acc += row[t] * W[t*256 + jj];
    if (k == 5) acc += (j < 256) ? bl0[jj] : br0[jj];
    Acat[k*512 + j] = acc;
}

__global__ void k_prep_t16(const float* __restrict__ Wl1, const float* __restrict__ bl1,
                           const float* __restrict__ Wr1, const float* __restrict__ br1,
                           const float* __restrict__ mlp_W,
                           _Float16* __restrict__ WlWr1t, float* __restrict__ blr1,
                           _Float16* __restrict__ mlpWt) {
    int n = blockIdx.x, k = threadIdx.x;
    if (n < 512) {
        float v = (n < 256) ? Wl1[k*256 + n] : Wr1[k*256 + (n - 256)];
        WlWr1t[n*256 + k] = (_Float16)v;
        if (k == 0) blr1[n] = (n < 256) ? bl1[n] : br1[n - 256];
    } else {
        int nn = n - 512;
        mlpWt[nn*256 + k] = (_Float16)mlp_W[k*64 + nn];
    }
}

// ---------------- streaming attr fp32->fp16 (+bias lane) with fused dst histogram ------
__global__ void k_conv_hist(const int* __restrict__ ei, const float* __restrict__ attr,
                            _Float16* __restrict__ attr16, int* __restrict__ counts) {
    int tid = threadIdx.x;
    int w = tid >> 6, lane = tid & 63;
    int e = blockIdx.x*4 + w;
    if (e >= EE) return;
    if (lane == 0) atomicAdd(&counts[ei[EE + e]], 1);
    float v = (lane < 63) ? attr[(size_t)e*63 + lane] : 1.0f;
    attr16[(size_t)e*64 + lane] = (_Float16)v;   // coalesced streaming write
}

__global__ __launch_bounds__(1024) void k_scan(const int* __restrict__ counts,
                                               int* __restrict__ row_ptr, int* __restrict__ cursor) {
    __shared__ int part[1024];
    int t = threadIdx.x;
    const int per = (NN + 1023) / 1024;
    int b0 = t*per, b1 = min(b0 + per, NN);
    int s = 0;
    for (int i = b0; i < b1; ++i) s += counts[i];
    part[t] = s; __syncthreads();
    for (int d = 1; d < 1024; d <<= 1) {
        int v = (t >= d) ? part[t-d] : 0;
        __syncthreads();
        part[t] += v;
        __syncthreads();
    }
    int run = (t == 0) ? 0 : part[t-1];
    for (int i = b0; i < b1; ++i) { row_ptr[i] = run; cursor[i] = run; run += counts[i]; }
    if (t == 0) row_ptr[NN] = EE;
}

// slim scatter: one packed {src, e} 8B random write per edge
__global__ void k_scatter(const int* __restrict__ ei, int* __restrict__ cursor,
                          int2* __restrict__ pair) {
    int e = blockIdx.x*256 + threadIdx.x;
    if (e < EE) {
        int d = ei[EE + e];
        int p = atomicAdd(&cursor[d], 1);
        pair[p] = make_int2(ei[e], e);
    }
}

// ---------------- layer 0 xl/xr via folded K=5 (fp16 out) ----------------
__global__ void k_xlxr0(const float* __restrict__ x, const float* __restrict__ Acat,
                        _Float16* __restrict__ xlxr16) {
    int n = blockIdx.x, j = threadIdx.x;
    float a0 = Acat[5*512 + j], a1 = Acat[5*512 + 256 + j];
#pragma unroll
    for (int k = 0; k < 5; ++k) {
        float xv = x[n*5 + k];
        a0 += xv * Acat[k*512 + j];
        a1 += xv * Acat[k*512 + 256 + j];
    }
    xlxr16[(size_t)n*512 + j] = (_Float16)a0;
    xlxr16[(size_t)n*512 + 256 + j] = (_Float16)a1;
}

// ---------------- fused GATv2 layer: low-VGPR, pair-indirect gathers, fused BN stats ----
// 2 nodes/block; wave w = head w. Depth-1 prefetch, Wpt B-fragments reloaded per tile (L1).
#define NPB 2

#define LOADT() { \
    int er = tl + srow; if (er >= el) er = el - 1; \
    const _Float16* sp = &xlxr16[(size_t)pairp[er].x*512 + wave*64 + scol]; \
    rx0 = *(const half8*)&sp[0]; \
    rx1 = *(const half8*)&sp[8]; \
    int arow = tl + l15; if (arow >= el) arow = el - 1; \
    const _Float16* ap = &attr16[(size_t)pairp[arow].y*64]; \
    ra0 = *(const half8*)&ap[l4*8]; \
    ra1 = *(const half8*)&ap[32 + l4*8]; \
    rxr = (float)xlxr16[(size_t)nl*512 + 256 + wave*64 + lane]; \
}

__global__ __launch_bounds__(256) void k_fused(const _Float16* __restrict__ attr16,
        const int2* __restrict__ pairp, const int* __restrict__ row_ptr,
        const _Float16* __restrict__ Wpt, const float* __restrict__ att,
        const _Float16* __restrict__ xlxr16, _Float16* __restrict__ gat16,
        float* __restrict__ stats) {
    int tid = threadIdx.x;
    int wave = tid >> 6, lane = tid & 63;
    int l15 = lane & 15, l4 = lane >> 4;
    int srow = lane >> 2, scol = (lane & 3) * 16;

    __shared__ __align__(16) _Float16 xls[4][16][72];   // wave-private single buffer

    // per-lane Wpt fragment base (fragments reloaded per tile from L1-resident 32KB table)
    const _Float16* bp = Wpt + (size_t)(wave*64 + l15)*64 + l4*8;
    float attv[4];
#pragma unroll
    for (int ct = 0; ct < 4; ++ct) attv[ct] = att[wave*64 + ct*16 + l15];

    int n0 = blockIdx.x*NPB;
    int nEnd = n0 + NPB; if (nEnd > NN) nEnd = NN;

    // zero-fill empty nodes; find first nonempty
    int nc = -1, tc = 0, ec = 0;
    for (int m = n0; m < nEnd; ++m) {
        int s = row_ptr[m], e = row_ptr[m+1];
        if (e <= s) gat16[(size_t)m*256 + wave*64 + lane] = (_Float16)0.f;
        else if (nc < 0) { nc = m; tc = s; ec = e; }
    }
    if (nc < 0) return;

    int nl = nc, tl = tc, el = ec;
    auto advIt = [&](int& n, int& t, int& e) -> bool {
        t += 16;
        if (t < e) return true;
        for (;;) {
            ++n;
            if (n >= nEnd) return false;
            int s = row_ptr[n]; e = row_ptr[n+1];
            if (e > s) { t = s; return true; }
        }
    };

    half8 rx0, rx1, ra0, ra1;
    float rxr;
    LOADT();
    bool haveL = advIt(nl, tl, el);

    float m_run = -3.0e38f, l_run = 0.f, out_acc = 0.f;
    float sAcc = 0.f, qAcc = 0.f;
    for (;;) {
        int nt = ec - tc; if (nt > 16) nt = 16;
        // stage current tile
        *(half8*)&xls[wave][srow][scol]     = rx0;
        *(half8*)&xls[wave][srow][scol + 8] = rx1;
        // MFMA with per-tile B-fragment reload (L1 hit)
        floatx4 acc[4];
#pragma unroll
        for (int ct = 0; ct < 4; ++ct) {
            half8 b0 = *(const half8*)(bp + ct*1024);
            half8 b1 = *(const half8*)(bp + ct*1024 + 32);
            floatx4 z = {};
            acc[ct] = __builtin_amdgcn_mfma_f32_16x16x32_f16(ra0, b0, z, 0, 0, 0);
            acc[ct] = __builtin_amdgcn_mfma_f32_16x16x32_f16(ra1, b1, acc[ct], 0, 0, 0);
        }
        // xr fragment via shuffle
        float xrf[4];
#pragma unroll
        for (int ct = 0; ct < 4; ++ct) xrf[ct] = __shfl(rxr, ct*16 + l15);
        // prefetch next tile (regs free after MFMA/shfl issue)
        if (haveL) { LOADT(); haveL = advIt(nl, tl, el); }
        // alpha combine (p[r] uniform within 16-lane group after reduce)
        float p[4];
#pragma unroll
        for (int r = 0; r < 4; ++r) {
            int eidx = l4*4 + r;
            float pv = 0.f;
#pragma unroll
            for (int ct = 0; ct < 4; ++ct) {
                float m = acc[ct][r] + (float)xls[wave][eidx][ct*16 + l15] + xrf[ct];
                float lr = fmaxf(m, 0.2f*m);
                pv += lr * attv[ct];
            }
            pv += __shfl_xor(pv, 1);
            pv += __shfl_xor(pv, 2);
            pv += __shfl_xor(pv, 4);
            pv += __shfl_xor(pv, 8);
            p[r] = (eidx < nt) ? pv : -3.0e38f;
        }
        // tile max: intra-lane over group's 4 edges, then cross-group
        float mt = fmaxf(fmaxf(p[0], p[1]), fmaxf(p[2], p[3]));
        mt = fmaxf(mt, __shfl_xor(mt, 16));
        mt = fmaxf(mt, __shfl_xor(mt, 32));
        float mnew = fmaxf(m_run, mt);
        float scale = __expf(m_run - mnew);
        out_acc *= scale; l_run *= scale;
        // 4 exps per lane (group-local), cross-group sum for denom
        float w4[4]; float wsum = 0.f;
#pragma unroll
        for (int r = 0; r < 4; ++r) { w4[r] = __expf(p[r] - mnew); wsum += w4[r]; }
        wsum += __shfl_xor(wsum, 16);
        wsum += __shfl_xor(wsum, 32);
        l_run += wsum;
        // accumulate: broadcast w (shfl) instead of recomputing exp
#pragma unroll
        for (int k = 0; k < 16; ++k) {
            float wk = __shfl(w4[k & 3], (k >> 2) << 4);
            out_acc += wk * (float)xls[wave][k][lane];
        }
        m_run = mnew;
        if (tc + 16 >= ec) {
            _Float16 h = (_Float16)(out_acc / l_run);
            gat16[(size_t)nc*256 + wave*64 + lane] = h;
            float hv = (float)h;
            sAcc += hv; qAcc += hv*hv;
            m_run = -3.0e38f; l_run = 0.f; out_acc = 0.f;
        }
        if (!advIt(nc, tc, ec)) break;
    }
    // fused BN stats: 16-sharded per-col partial sums
    int shard = blockIdx.x & 15;
    atomicAdd(&stats[shard*512 + wave*64 + lane], sAcc);
    atomicAdd(&stats[shard*512 + 256 + wave*64 + lane], qAcc);
}

__global__ void k_bn_final(const float* __restrict__ stats, const float* __restrict__ gamma,
                           const float* __restrict__ beta, float* __restrict__ ss) {
    int j = threadIdx.x;
    float s = 0.f, q = 0.f;
#pragma unroll
    for (int sh = 0; sh < 16; ++sh) {
        s += stats[sh*512 + j];
        q += stats[sh*512 + 256 + j];
    }
    float mean = s * (1.0f/NN);
    float var  = q * (1.0f/NN) - mean*mean;
    float sc = rsqrtf(var + 1e-5f) * gamma[j];
    ss[j] = sc;
    ss[256 + j] = beta[j] - mean*sc;
}

// ---------------- fp16 MFMA GEMM with fused BN+ReLU on A ----------------
template<bool RELU, typename OT>
__global__ __launch_bounds__(256) void k_gemm(const _Float16* __restrict__ A,
                       const float* __restrict__ ssv,
                       const _Float16* __restrict__ Bt,
                       const float* __restrict__ bias, OT* __restrict__ C,
                       int M, int ldc) {
    __shared__ __align__(16) _Float16 As[128][72];
    __shared__ __align__(16) _Float16 Bs[64][72];
    int tid = threadIdx.x;
    int wave = tid >> 6, lane = tid & 63;
    int l15 = lane & 15, l4 = lane >> 4;
    int row0 = blockIdx.x*128, n0 = blockIdx.y*64;
    floatx4 acc[2][4] = {};
    for (int k0 = 0; k0 < 256; k0 += 64) {
#pragma unroll
        for (int q = 0; q < 4; ++q) {
            int c = tid + q*256;
            int r = c >> 3, kc = (c & 7)*8;
            int gr = row0 + r; if (gr >= M) gr = M - 1;
            half8 g = *(const half8*)&A[(size_t)gr*256 + k0 + kc];
            _Float16 tmp[8];
#pragma unroll
            for (int i = 0; i < 8; ++i) {
                int colk = k0 + kc + i;
                float v = (float)g[i]*ssv[colk] + ssv[256 + colk];
                tmp[i] = (_Float16)fmaxf(v, 0.f);
            }
            *(half8*)&As[r][kc] = *(half8*)tmp;
        }
#pragma unroll
        for (int q = 0; q < 2; ++q) {
            int c = tid + q*256;
            int r = c >> 3, kc = (c & 7)*8;
            *(half8*)&Bs[r][kc] = *(const half8*)&Bt[(size_t)(n0 + r)*256 + k0 + kc];
        }
        __syncthreads();
#pragma unroll
        for (int ks = 0; ks < 64; ks += 32) {
            half8 a0 = *(const half8*)&As[wave*32 + l15][ks + l4*8];
            half8 a1 = *(const half8*)&As[wave*32 + 16 + l15][ks + l4*8];
#pragma unroll
            for (int nb = 0; nb < 4; ++nb) {
                half8 b = *(const half8*)&Bs[nb*16 + l15][ks + l4*8];
                acc[0][nb] = __builtin_amdgcn_mfma_f32_16x16x32_f16(a0, b, acc[0][nb], 0, 0, 0);
                acc[1][nb] = __builtin_amdgcn_mfma_f32_16x16x32_f16(a1, b, acc[1][nb], 0, 0, 0);
            }
        }
        __syncthreads();
    }
#pragma unroll
    for (int m = 0; m < 2; ++m)
#pragma unroll
    for (int nb = 0; nb < 4; ++nb) {
        int col = n0 + nb*16 + l15;
        float bv = bias[col];
#pragma unroll
        for (int r = 0; r < 4; ++r) {
            int grow = row0 + wave*32 + m*16 + l4*4 + r;
            if (grow < M) {
                float v = acc[m][nb][r] + bv;
                if (RELU) v = fmaxf(v, 0.f);
                C[(size_t)grow*ldc + col] = (OT)v;
            }
        }
    }
}

// ---------------- pooling (batch sorted -> contiguous ranges, no atomics) ----------------
__global__ void k_pool2(const float* __restrict__ mo, const int* __restrict__ batch,
                        float* __restrict__ pooledDiv) {
    int b = blockIdx.x;
    int j = threadIdx.x & 63, rg = threadIdx.x >> 6;
    int lo = 0, hi = NN;
    while (lo < hi) { int mid = (lo + hi) >> 1; if (batch[mid] < b) lo = mid + 1; else hi = mid; }
    int s = lo;
    lo = 0; hi = NN;
    while (lo < hi) { int mid = (lo + hi) >> 1; if (batch[mid] < b + 1) lo = mid + 1; else hi = mid; }
    int e = lo;
    float acc = 0.f;
    for (int r = s + rg; r < e; r += 4) acc += mo[(size_t)r*64 + j];
    __shared__ float red[256];
    red[threadIdx.x] = acc;
    __syncthreads();
    if (rg == 0) {
        float v = red[j] + red[64 + j] + red[128 + j] + red[192 + j];
        pooledDiv[b*64 + j] = v / fmaxf((float)(e - s), 1.f);
    }
}

__global__ void k_final(const float* __restrict__ pooledDiv,
                        const float* __restrict__ outW, const float* __restrict__ outb,
                        float* __restrict__ out) {
    int t = threadIdx.x;
    if (t >= 320) return;
    int b = t / 5, c = t % 5;
    float acc = outb[c];
    for (int k = 0; k < 64; ++k) acc += pooledDiv[b*64 + k] * outW[k*5 + c];
    out[t] = acc;
}

extern "C" void kernel_launch(void* const* d_in, const int* in_sizes, int n_in,
                              void* d_out, int out_size, void* d_ws, size_t ws_size,
                              hipStream_t stream) {
    const float* x      = (const float*)d_in[0];
    const int*   ei     = (const int*)d_in[1];
    const float* attr   = (const float*)d_in[2];
    const int*   batch  = (const int*)d_in[3];
    const float* node_W = (const float*)d_in[4];
    const float* node_b = (const float*)d_in[5];
    const float* edge_W = (const float*)d_in[6];
    const float* edge_b = (const float*)d_in[7];
    const float* Wl[2]   = {(const float*)d_in[8],  (const float*)d_in[17]};
    const float* bl[2]   = {(const float*)d_in[9],  (const float*)d_in[18]};
    const float* Wr[2]   = {(const float*)d_in[10], (const float*)d_in[19]};
    const float* br[2]   = {(const float*)d_in[11], (const float*)d_in[20]};
    const float* We[2]   = {(const float*)d_in[12], (const float*)d_in[21]};
    const float* att[2]  = {(const float*)d_in[13], (const float*)d_in[22]};
    const float* gamma[2]= {(const float*)d_in[15], (const float*)d_in[24]};
    const float* beta[2] = {(const float*)d_in[16], (const float*)d_in[25]};
    const float* mlp_W = (const float*)d_in[26];
    const float* mlp_b = (const float*)d_in[27];
    const float* out_W = (const float*)d_in[28];
    const float* out_b = (const float*)d_in[29];
    float* out = (float*)d_out;

    char* p = (char*)d_ws;
    size_t off = 0;
    auto carve = [&](size_t bytes) -> void* {
        void* r = p + off;
        off = (off + bytes + 255) & ~(size_t)255;
        return r;
    };
    _Float16* Wpt0   = (_Float16*)carve(256*64*2);
    _Float16* Wpt1   = (_Float16*)carve(256*64*2);
    float*    Acat   = (float*)carve(6*512*4);
    _Float16* WlWr1t = (_Float16*)carve(512*256*2);
    float*    blr1   = (float*)carve(512*4);
    _Float16* mlpWt  = (_Float16*)carve(64*256*2);
    float*    ss     = (float*)carve(512*4);
    _Float16* xlxr16 = (_Float16*)carve((size_t)NN*512*2);
    _Float16* gat16  = (_Float16*)carve((size_t)NN*256*2);
    float*    mlo    = (float*)carve((size_t)NN*64*4);
    _Float16* attr16 = (_Float16*)carve((size_t)EE*64*2);
    int*      row_ptr= (int*)carve((NN+1)*4);
    int2*     pairA  = (int2*)carve((size_t)EE*8);
    int*      cursor = (int*)carve(NN*4);
    float*    pooledDiv = (float*)carve(BB*64*4);
    char*     zz     = (char*)carve((NN + 2*16*512)*4);
    int*      counts = (int*)zz;
    float*    stats  = (float*)(zz + (size_t)NN*4);   // 2 layers x 16 shards x 512
    if (off > ws_size) return;  // workspace too small: bail

    hipMemsetAsync(zz, 0, (size_t)(NN + 2*16*512)*4, stream);
    k_prep_edgeW<<<dim3(64,2), 256, 0, stream>>>(edge_W, edge_b, We[0], We[1], Wpt0, Wpt1);
    k_prep_acat<<<6, 512, 0, stream>>>(node_W, node_b, Wl[0], bl[0], Wr[0], br[0], Acat);
    k_prep_t16<<<576, 256, 0, stream>>>(Wl[1], bl[1], Wr[1], br[1], mlp_W, WlWr1t, blr1, mlpWt);
    k_conv_hist<<<EE/4, 256, 0, stream>>>(ei, attr, attr16, counts);
    k_scan<<<1, 1024, 0, stream>>>(counts, row_ptr, cursor);
    k_scatter<<<(EE+255)/256, 256, 0, stream>>>(ei, cursor, pairA);
    k_xlxr0<<<NN, 256, 0, stream>>>(x, Acat, xlxr16);

    for (int L = 0; L < 2; ++L) {
        k_fused<<<(NN + NPB - 1)/NPB, 256, 0, stream>>>(attr16, pairA, row_ptr,
                 L ? Wpt1 : Wpt0, att[L], xlxr16, gat16, stats + L*8192);
        k_bn_final<<<1, 256, 0, stream>>>(stats + L*8192, gamma[L], beta[L], ss);
        if (L == 0)
            k_gemm<false, _Float16><<<dim3(157, 8), 256, 0, stream>>>(gat16, ss, WlWr1t, blr1, xlxr16, NN, 512);
        else
            k_gemm<true, float><<<dim3(157, 1), 256, 0, stream>>>(gat16, ss, mlpWt, mlp_b, mlo, NN, 64);
    }
    k_pool2<<<BB, 256, 0, stream>>>(mlo, batch, pooledDiv);
    k_final<<<1, 320, 0, stream>>>(pooledDiv, out_W, out_b, out);
}

// Round 17
// 402.935 us; speedup vs baseline: 1.0470x; 1.0397x over previous
//
#include <hip/hip_runtime.h>

#define NN 20000
#define EE 320000
#define BB 64

typedef _Float16 half8 __attribute__((ext_vector_type(8)));
typedef float floatx4 __attribute__((ext_vector_type(4)));

// ---------------- prep: weight folding ----------------
__global__ void k_prep_edgeW(const float* __restrict__ edge_W, const float* __restrict__ edge_b,
                             const float* __restrict__ We0, const float* __restrict__ We1,
                             _Float16* __restrict__ Wpt0, _Float16* __restrict__ Wpt1) {
    __shared__ float row[256];
    int k = blockIdx.x, layer = blockIdx.y, j = threadIdx.x;
    row[j] = (k < 63) ? edge_W[k*256 + j] : edge_b[j];
    __syncthreads();
    const float* We = layer ? We1 : We0;
    float acc = 0.f;
    for (int t = 0; t < 256; ++t) acc += row[t] * We[t*256 + j];
    (layer ? Wpt1 : Wpt0)[j*64 + k] = (_Float16)acc;   // transposed [col][k] fp16
}

__global__ void k_prep_acat(const float* __restrict__ node_W, const float* __restrict__ node_b,
                            const float* __restrict__ Wl0, const float* __restrict__ bl0,
                            const float* __restrict__ Wr0, const float* __restrict__ br0,
                            float* __restrict__ Acat) {
    __shared__ float row[256];
    int k = blockIdx.x, j = threadIdx.x;
    if (j < 256) row[j] = (k < 5) ? node_W[k*256 + j] : node_b[j];
    __syncthreads();
    int jj = j & 255;
    const float* W = (j < 256) ? Wl0 : Wr0;
    float acc = 0.f;
    for (int t = 0; t < 256; ++t) acc += row[t] * W[t*256 + jj];
    if (k == 5) acc += (j < 256) ? bl0[jj] : br0[jj];
    Acat[k*512 + j] = acc;
}

__global__ void k_prep_t16(const float* __restrict__ Wl1, const float* __restrict__ bl1,
                           const float* __restrict__ Wr1, const float* __restrict__ br1,
                           const float* __restrict__ mlp_W,
                           _Float16* __restrict__ WlWr1t, float* __restrict__ blr1,
                           _Float16* __restrict__ mlpWt) {
    int n = blockIdx.x, k = threadIdx.x;
    if (n < 512) {
        float v = (n < 256) ? Wl1[k*256 + n] : Wr1[k*256 + (n - 256)];
        WlWr1t[n*256 + k] = (_Float16)v;
        if (k == 0) blr1[n] = (n < 256) ? bl1[n] : br1[n - 256];
    } else {
        int nn = n - 512;
        mlpWt[nn*256 + k] = (_Float16)mlp_W[k*64 + nn];
    }
}

// ---------------- streaming attr fp32->fp16 (+bias lane) with fused dst histogram ------
__global__ void k_conv_hist(const int* __restrict__ ei, const float* __restrict__ attr,
                            _Float16* __restrict__ attr16, int* __restrict__ counts) {
    int tid = threadIdx.x;
    int w = tid >> 6, lane = tid & 63;
    int e = blockIdx.x*4 + w;
    if (e >= EE) return;
    if (lane == 0) atomicAdd(&counts[ei[EE + e]], 1);
    float v = (lane < 63) ? attr[(size_t)e*63 + lane] : 1.0f;
    attr16[(size_t)e*64 + lane] = (_Float16)v;   // coalesced streaming write
}

__global__ __launch_bounds__(1024) void k_scan(const int* __restrict__ counts,
                                               int* __restrict__ row_ptr, int* __restrict__ cursor) {
    __shared__ int part[1024];
    int t = threadIdx.x;
    const int per = (NN + 1023) / 1024;
    int b0 = t*per, b1 = min(b0 + per, NN);
    int s = 0;
    for (int i = b0; i < b1; ++i) s += counts[i];
    part[t] = s; __syncthreads();
    for (int d = 1; d < 1024; d <<= 1) {
        int v = (t >= d) ? part[t-d] : 0;
        __syncthreads();
        part[t] += v;
        __syncthreads();
    }
    int run = (t == 0) ? 0 : part[t-1];
    for (int i = b0; i < b1; ++i) { row_ptr[i] = run; cursor[i] = run; run += counts[i]; }
    if (t == 0) row_ptr[NN] = EE;
}

// slim scatter: one packed {src, e} 8B random write per edge
__global__ void k_scatter(const int* __restrict__ ei, int* __restrict__ cursor,
                          int2* __restrict__ pair) {
    int e = blockIdx.x*256 + threadIdx.x;
    if (e < EE) {
        int d = ei[EE + e];
        int p = atomicAdd(&cursor[d], 1);
        pair[p] = make_int2(ei[e], e);
    }
}

// ---------------- layer 0 xl/xr via folded K=5 (fp16 out) ----------------
__global__ void k_xlxr0(const float* __restrict__ x, const float* __restrict__ Acat,
                        _Float16* __restrict__ xlxr16) {
    int n = blockIdx.x, j = threadIdx.x;
    float a0 = Acat[5*512 + j], a1 = Acat[5*512 + 256 + j];
#pragma unroll
    for (int k = 0; k < 5; ++k) {
        float xv = x[n*5 + k];
        a0 += xv * Acat[k*512 + j];
        a1 += xv * Acat[k*512 + 256 + j];
    }
    xlxr16[(size_t)n*512 + j] = (_Float16)a0;
    xlxr16[(size_t)n*512 + 256 + j] = (_Float16)a1;
}

// ---------------- fused GATv2 layer: low-VGPR, pair-indirect gathers, fused BN stats ----
// 4 nodes/block; wave w = head w. Depth-1 prefetch, Wpt B-fragments reloaded per tile (L1).
#define NPB 4

#define LOADT() { \
    int er = tl + srow; if (er >= el) er = el - 1; \
    const _Float16* sp = &xlxr16[(size_t)pairp[er].x*512 + wave*64 + scol]; \
    rx0 = *(const half8*)&sp[0]; \
    rx1 = *(const half8*)&sp[8]; \
    int arow = tl + l15; if (arow >= el) arow = el - 1; \
    const _Float16* ap = &attr16[(size_t)pairp[arow].y*64]; \
    ra0 = *(const half8*)&ap[l4*8]; \
    ra1 = *(const half8*)&ap[32 + l4*8]; \
    rxr = (float)xlxr16[(size_t)nl*512 + 256 + wave*64 + lane]; \
}

__global__ __launch_bounds__(256) void k_fused(const _Float16* __restrict__ attr16,
        const int2* __restrict__ pairp, const int* __restrict__ row_ptr,
        const _Float16* __restrict__ Wpt, const float* __restrict__ att,
        const _Float16* __restrict__ xlxr16, _Float16* __restrict__ gat16,
        float* __restrict__ stats) {
    int tid = threadIdx.x;
    int wave = tid >> 6, lane = tid & 63;
    int l15 = lane & 15, l4 = lane >> 4;
    int srow = lane >> 2, scol = (lane & 3) * 16;

    __shared__ __align__(16) _Float16 xls[4][16][72];   // wave-private single buffer

    // per-lane Wpt fragment base (fragments reloaded per tile from L1-resident 32KB table)
    const _Float16* bp = Wpt + (size_t)(wave*64 + l15)*64 + l4*8;
    float attv[4];
#pragma unroll
    for (int ct = 0; ct < 4; ++ct) attv[ct] = att[wave*64 + ct*16 + l15];

    int n0 = blockIdx.x*NPB;
    int nEnd = n0 + NPB; if (nEnd > NN) nEnd = NN;

    // zero-fill empty nodes; find first nonempty
    int nc = -1, tc = 0, ec = 0;
    for (int m = n0; m < nEnd; ++m) {
        int s = row_ptr[m], e = row_ptr[m+1];
        if (e <= s) gat16[(size_t)m*256 + wave*64 + lane] = (_Float16)0.f;
        else if (nc < 0) { nc = m; tc = s; ec = e; }
    }
    if (nc < 0) return;

    int nl = nc, tl = tc, el = ec;
    auto advIt = [&](int& n, int& t, int& e) -> bool {
        t += 16;
        if (t < e) return true;
        for (;;) {
            ++n;
            if (n >= nEnd) return false;
            int s = row_ptr[n]; e = row_ptr[n+1];
            if (e > s) { t = s; return true; }
        }
    };

    half8 rx0, rx1, ra0, ra1;
    float rxr;
    LOADT();
    bool haveL = advIt(nl, tl, el);

    float m_run = -3.0e38f, l_run = 0.f, out_acc = 0.f;
    float sAcc = 0.f, qAcc = 0.f;
    for (;;) {
        int nt = ec - tc; if (nt > 16) nt = 16;
        // stage current tile
        *(half8*)&xls[wave][srow][scol]     = rx0;
        *(half8*)&xls[wave][srow][scol + 8] = rx1;
        // MFMA with per-tile B-fragment reload (L1 hit)
        floatx4 acc[4];
#pragma unroll
        for (int ct = 0; ct < 4; ++ct) {
            half8 b0 = *(const half8*)(bp + ct*1024);
            half8 b1 = *(const half8*)(bp + ct*1024 + 32);
            floatx4 z = {};
            acc[ct] = __builtin_amdgcn_mfma_f32_16x16x32_f16(ra0, b0, z, 0, 0, 0);
            acc[ct] = __builtin_amdgcn_mfma_f32_16x16x32_f16(ra1, b1, acc[ct], 0, 0, 0);
        }
        // xr fragment via shuffle
        float xrf[4];
#pragma unroll
        for (int ct = 0; ct < 4; ++ct) xrf[ct] = __shfl(rxr, ct*16 + l15);
        // prefetch next tile (regs free after MFMA/shfl issue)
        if (haveL) { LOADT(); haveL = advIt(nl, tl, el); }
        // alpha combine (p[r] uniform within 16-lane group after reduce)
        float p[4];
#pragma unroll
        for (int r = 0; r < 4; ++r) {
            int eidx = l4*4 + r;
            float pv = 0.f;
#pragma unroll
            for (int ct = 0; ct < 4; ++ct) {
                float m = acc[ct][r] + (float)xls[wave][eidx][ct*16 + l15] + xrf[ct];
                float lr = fmaxf(m, 0.2f*m);
                pv += lr * attv[ct];
            }
            pv += __shfl_xor(pv, 1);
            pv += __shfl_xor(pv, 2);
            pv += __shfl_xor(pv, 4);
            pv += __shfl_xor(pv, 8);
            p[r] = (eidx < nt) ? pv : -3.0e38f;
        }
        // tile max: intra-lane over group's 4 edges, then cross-group
        float mt = fmaxf(fmaxf(p[0], p[1]), fmaxf(p[2], p[3]));
        mt = fmaxf(mt, __shfl_xor(mt, 16));
        mt = fmaxf(mt, __shfl_xor(mt, 32));
        float mnew = fmaxf(m_run, mt);
        float scale = __expf(m_run - mnew);
        out_acc *= scale; l_run *= scale;
        // 4 exps per lane (group-local), cross-group sum for denom
        float w4[4]; float wsum = 0.f;
#pragma unroll
        for (int r = 0; r < 4; ++r) { w4[r] = __expf(p[r] - mnew); wsum += w4[r]; }
        wsum += __shfl_xor(wsum, 16);
        wsum += __shfl_xor(wsum, 32);
        l_run += wsum;
        // accumulate: broadcast w (shfl) instead of recomputing exp
#pragma unroll
        for (int k = 0; k < 16; ++k) {
            float wk = __shfl(w4[k & 3], (k >> 2) << 4);
            out_acc += wk * (float)xls[wave][k][lane];
        }
        m_run = mnew;
        if (tc + 16 >= ec) {
            _Float16 h = (_Float16)(out_acc / l_run);
            gat16[(size_t)nc*256 + wave*64 + lane] = h;
            float hv = (float)h;
            sAcc += hv; qAcc += hv*hv;
            m_run = -3.0e38f; l_run = 0.f; out_acc = 0.f;
        }
        if (!advIt(nc, tc, ec)) break;
    }
    // fused BN stats: 16-sharded per-col partial sums
    int shard = blockIdx.x & 15;
    atomicAdd(&stats[shard*512 + wave*64 + lane], sAcc);
    atomicAdd(&stats[shard*512 + 256 + wave*64 + lane], qAcc);
}

__global__ void k_bn_final(const float* __restrict__ stats, const float* __restrict__ gamma,
                           const float* __restrict__ beta, float* __restrict__ ss) {
    int j = threadIdx.x;
    float s = 0.f, q = 0.f;
#pragma unroll
    for (int sh = 0; sh < 16; ++sh) {
        s += stats[sh*512 + j];
        q += stats[sh*512 + 256 + j];
    }
    float mean = s * (1.0f/NN);
    float var  = q * (1.0f/NN) - mean*mean;
    float sc = rsqrtf(var + 1e-5f) * gamma[j];
    ss[j] = sc;
    ss[256 + j] = beta[j] - mean*sc;
}

// ---------------- fp16 MFMA GEMM with fused BN+ReLU on A ----------------
template<bool RELU, typename OT>
__global__ __launch_bounds__(256) void k_gemm(const _Float16* __restrict__ A,
                       const float* __restrict__ ssv,
                       const _Float16* __restrict__ Bt,
                       const float* __restrict__ bias, OT* __restrict__ C,
                       int M, int ldc) {
    __shared__ __align__(16) _Float16 As[128][72];
    __shared__ __align__(16) _Float16 Bs[64][72];
    int tid = threadIdx.x;
    int wave = tid >> 6, lane = tid & 63;
    int l15 = lane & 15, l4 = lane >> 4;
    int row0 = blockIdx.x*128, n0 = blockIdx.y*64;
    floatx4 acc[2][4] = {};
    for (int k0 = 0; k0 < 256; k0 += 64) {
#pragma unroll
        for (int q = 0; q < 4; ++q) {
            int c = tid + q*256;
            int r = c >> 3, kc = (c & 7)*8;
            int gr = row0 + r; if (gr >= M) gr = M - 1;
            half8 g = *(const half8*)&A[(size_t)gr*256 + k0 + kc];
            _Float16 tmp[8];
#pragma unroll
            for (int i = 0; i < 8; ++i) {
                int colk = k0 + kc + i;
                float v = (float)g[i]*ssv[colk] + ssv[256 + colk];
                tmp[i] = (_Float16)fmaxf(v, 0.f);
            }
            *(half8*)&As[r][kc] = *(half8*)tmp;
        }
#pragma unroll
        for (int q = 0; q < 2; ++q) {
            int c = tid + q*256;
            int r = c >> 3, kc = (c & 7)*8;
            *(half8*)&Bs[r][kc] = *(const half8*)&Bt[(size_t)(n0 + r)*256 + k0 + kc];
        }
        __syncthreads();
#pragma unroll
        for (int ks = 0; ks < 64; ks += 32) {
            half8 a0 = *(const half8*)&As[wave*32 + l15][ks + l4*8];
            half8 a1 = *(const half8*)&As[wave*32 + 16 + l15][ks + l4*8];
#pragma unroll
            for (int nb = 0; nb < 4; ++nb) {
                half8 b = *(const half8*)&Bs[nb*16 + l15][ks + l4*8];
                acc[0][nb] = __builtin_amdgcn_mfma_f32_16x16x32_f16(a0, b, acc[0][nb], 0, 0, 0);
                acc[1][nb] = __builtin_amdgcn_mfma_f32_16x16x32_f16(a1, b, acc[1][nb], 0, 0, 0);
            }
        }
        __syncthreads();
    }
#pragma unroll
    for (int m = 0; m < 2; ++m)
#pragma unroll
    for (int nb = 0; nb < 4; ++nb) {
        int col = n0 + nb*16 + l15;
        float bv = bias[col];
#pragma unroll
        for (int r = 0; r < 4; ++r) {
            int grow = row0 + wave*32 + m*16 + l4*4 + r;
            if (grow < M) {
                float v = acc[m][nb][r] + bv;
                if (RELU) v = fmaxf(v, 0.f);
                C[(size_t)grow*ldc + col] = (OT)v;
            }
        }
    }
}

// ---------------- pooling (batch sorted -> contiguous ranges, no atomics) ----------------
__global__ void k_pool2(const float* __restrict__ mo, const int* __restrict__ batch,
                        float* __restrict__ pooledDiv) {
    int b = blockIdx.x;
    int j = threadIdx.x & 63, rg = threadIdx.x >> 6;
    int lo = 0, hi = NN;
    while (lo < hi) { int mid = (lo + hi) >> 1; if (batch[mid] < b) lo = mid + 1; else hi = mid; }
    int s = lo;
    lo = 0; hi = NN;
    while (lo < hi) { int mid = (lo + hi) >> 1; if (batch[mid] < b + 1) lo = mid + 1; else hi = mid; }
    int e = lo;
    float acc = 0.f;
    for (int r = s + rg; r < e; r += 4) acc += mo[(size_t)r*64 + j];
    __shared__ float red[256];
    red[threadIdx.x] = acc;
    __syncthreads();
    if (rg == 0) {
        float v = red[j] + red[64 + j] + red[128 + j] + red[192 + j];
        pooledDiv[b*64 + j] = v / fmaxf((float)(e - s), 1.f);
    }
}

__global__ void k_final(const float* __restrict__ pooledDiv,
                        const float* __restrict__ outW, const float* __restrict__ outb,
                        float* __restrict__ out) {
    int t = threadIdx.x;
    if (t >= 320) return;
    int b = t / 5, c = t % 5;
    float acc = outb[c];
    for (int k = 0; k < 64; ++k) acc += pooledDiv[b*64 + k] * outW[k*5 + c];
    out[t] = acc;
}

extern "C" void kernel_launch(void* const* d_in, const int* in_sizes, int n_in,
                              void* d_out, int out_size, void* d_ws, size_t ws_size,
                              hipStream_t stream) {
    const float* x      = (const float*)d_in[0];
    const int*   ei     = (const int*)d_in[1];
    const float* attr   = (const float*)d_in[2];
    const int*   batch  = (const int*)d_in[3];
    const float* node_W = (const float*)d_in[4];
    const float* node_b = (const float*)d_in[5];
    const float* edge_W = (const float*)d_in[6];
    const float* edge_b = (const float*)d_in[7];
    const float* Wl[2]   = {(const float*)d_in[8],  (const float*)d_in[17]};
    const float* bl[2]   = {(const float*)d_in[9],  (const float*)d_in[18]};
    const float* Wr[2]   = {(const float*)d_in[10], (const float*)d_in[19]};
    const float* br[2]   = {(const float*)d_in[11], (const float*)d_in[20]};
    const float* We[2]   = {(const float*)d_in[12], (const float*)d_in[21]};
    const float* att[2]  = {(const float*)d_in[13], (const float*)d_in[22]};
    const float* gamma[2]= {(const float*)d_in[15], (const float*)d_in[24]};
    const float* beta[2] = {(const float*)d_in[16], (const float*)d_in[25]};
    const float* mlp_W = (const float*)d_in[26];
    const float* mlp_b = (const float*)d_in[27];
    const float* out_W = (const float*)d_in[28];
    const float* out_b = (const float*)d_in[29];
    float* out = (float*)d_out;

    char* p = (char*)d_ws;
    size_t off = 0;
    auto carve = [&](size_t bytes) -> void* {
        void* r = p + off;
        off = (off + bytes + 255) & ~(size_t)255;
        return r;
    };
    _Float16* Wpt0   = (_Float16*)carve(256*64*2);
    _Float16* Wpt1   = (_Float16*)carve(256*64*2);
    float*    Acat   = (float*)carve(6*512*4);
    _Float16* WlWr1t = (_Float16*)carve(512*256*2);
    float*    blr1   = (float*)carve(512*4);
    _Float16* mlpWt  = (_Float16*)carve(64*256*2);
    float*    ss     = (float*)carve(512*4);
    _Float16* xlxr16 = (_Float16*)carve((size_t)NN*512*2);
    _Float16* gat16  = (_Float16*)carve((size_t)NN*256*2);
    float*    mlo    = (float*)carve((size_t)NN*64*4);
    _Float16* attr16 = (_Float16*)carve((size_t)EE*64*2);
    int*      row_ptr= (int*)carve((NN+1)*4);
    int2*     pairA  = (int2*)carve((size_t)EE*8);
    int*      cursor = (int*)carve(NN*4);
    float*    pooledDiv = (float*)carve(BB*64*4);
    char*     zz     = (char*)carve((NN + 2*16*512)*4);
    int*      counts = (int*)zz;
    float*    stats  = (float*)(zz + (size_t)NN*4);   // 2 layers x 16 shards x 512
    if (off > ws_size) return;  // workspace too small: bail

    hipMemsetAsync(zz, 0, (size_t)(NN + 2*16*512)*4, stream);
    k_prep_edgeW<<<dim3(64,2), 256, 0, stream>>>(edge_W, edge_b, We[0], We[1], Wpt0, Wpt1);
    k_prep_acat<<<6, 512, 0, stream>>>(node_W, node_b, Wl[0], bl[0], Wr[0], br[0], Acat);
    k_prep_t16<<<576, 256, 0, stream>>>(Wl[1], bl[1], Wr[1], br[1], mlp_W, WlWr1t, blr1, mlpWt);
    k_conv_hist<<<EE/4, 256, 0, stream>>>(ei, attr, attr16, counts);
    k_scan<<<1, 1024, 0, stream>>>(counts, row_ptr, cursor);
    k_scatter<<<(EE+255)/256, 256, 0, stream>>>(ei, cursor, pairA);
    k_xlxr0<<<NN, 256, 0, stream>>>(x, Acat, xlxr16);

    for (int L = 0; L < 2; ++L) {
        k_fused<<<(NN + NPB - 1)/NPB, 256, 0, stream>>>(attr16, pairA, row_ptr,
                 L ? Wpt1 : Wpt0, att[L], xlxr16, gat16, stats + L*8192);
        k_bn_final<<<1, 256, 0, stream>>>(stats + L*8192, gamma[L], beta[L], ss);
        if (L == 0)
            k_gemm<false, _Float16><<<dim3(157, 8), 256, 0, stream>>>(gat16, ss, WlWr1t, blr1, xlxr16, NN, 512);
        else
            k_gemm<true, float><<<dim3(157, 1), 256, 0, stream>>>(gat16, ss, mlpWt, mlp_b, mlo, NN, 64);
    }
    k_pool2<<<BB, 256, 0, stream>>>(mlo, batch, pooledDiv);
    k_final<<<1, 320, 0, stream>>>(pooledDiv, out_W, out_b, out);
}

// Round 18
// 387.474 us; speedup vs baseline: 1.0888x; 1.0399x over previous
//
#include <hip/hip_runtime.h>

#define NN 20000
#define EE 320000
#define BB 64

typedef _Float16 half8 __attribute__((ext_vector_type(8)));
typedef float floatx4 __attribute__((ext_vector_type(4)));

// ---------------- prep: weight folding (+ zero counts) ----------------
__global__ void k_prep_edgeW(const float* __restrict__ edge_W, const float* __restrict__ edge_b,
                             const float* __restrict__ We0, const float* __restrict__ We1,
                             _Float16* __restrict__ Wpt0, _Float16* __restrict__ Wpt1,
                             int* __restrict__ counts) {
    __shared__ float row[256];
    int k = blockIdx.x, layer = blockIdx.y, j = threadIdx.x;
    int gid = (blockIdx.y*64 + blockIdx.x)*256 + j;
    if (gid < NN) counts[gid] = 0;
    row[j] = (k < 63) ? edge_W[k*256 + j] : edge_b[j];
    __syncthreads();
    const float* We = layer ? We1 : We0;
    float acc = 0.f;
    for (int t = 0; t < 256; ++t) acc += row[t] * We[t*256 + j];
    (layer ? Wpt1 : Wpt0)[j*64 + k] = (_Float16)acc;   // transposed [col][k] fp16
}

__global__ void k_prep_acat(const float* __restrict__ node_W, const float* __restrict__ node_b,
                            const float* __restrict__ Wl0, const float* __restrict__ bl0,
                            const float* __restrict__ Wr0, const float* __restrict__ br0,
                            float* __restrict__ Acat) {
    __shared__ float row[256];
    int k = blockIdx.x, j = threadIdx.x;
    if (j < 256) row[j] = (k < 5) ? node_W[k*256 + j] : node_b[j];
    __syncthreads();
    int jj = j & 255;
    const float* W = (j < 256) ? Wl0 : Wr0;
    float acc = 0.f;
    for (int t = 0; t < 256; ++t) acc += row[t] * W[t*256 + jj];
    if (k == 5) acc += (j < 256) ? bl0[jj] : br0[jj];
    Acat[k*512 + j] = acc;
}

// transpose+fp16 (+ zero stats: 2 layers x 16 shards x 512)
__global__ void k_prep_t16(const float* __restrict__ Wl1, const float* __restrict__ bl1,
                           const float* __restrict__ Wr1, const float* __restrict__ br1,
                           const float* __restrict__ mlp_W,
                           _Float16* __restrict__ WlWr1t, float* __restrict__ blr1,
                           _Float16* __restrict__ mlpWt, float* __restrict__ stats) {
    int n = blockIdx.x, k = threadIdx.x;
    int gid = n*256 + k;
    if (gid < 2*16*512) stats[gid] = 0.f;
    if (n < 512) {
        float v = (n < 256) ? Wl1[k*256 + n] : Wr1[k*256 + (n - 256)];
        WlWr1t[n*256 + k] = (_Float16)v;
        if (k == 0) blr1[n] = (n < 256) ? bl1[n] : br1[n - 256];
    } else {
        int nn = n - 512;
        mlpWt[nn*256 + k] = (_Float16)mlp_W[k*64 + nn];
    }
}

// ---------------- streaming attr fp32->fp16 (+bias lane) with fused dst histogram ------
__global__ void k_conv_hist(const int* __restrict__ ei, const float* __restrict__ attr,
                            _Float16* __restrict__ attr16, int* __restrict__ counts) {
    int tid = threadIdx.x;
    int w = tid >> 6, lane = tid & 63;
    int e = blockIdx.x*4 + w;
    if (e >= EE) return;
    if (lane == 0) atomicAdd(&counts[ei[EE + e]], 1);
    float v = (lane < 63) ? attr[(size_t)e*63 + lane] : 1.0f;
    attr16[(size_t)e*64 + lane] = (_Float16)v;   // coalesced streaming write
}

__global__ __launch_bounds__(1024) void k_scan(const int* __restrict__ counts,
                                               int* __restrict__ row_ptr, int* __restrict__ cursor) {
    __shared__ int part[1024];
    int t = threadIdx.x;
    const int per = (NN + 1023) / 1024;
    int b0 = t*per, b1 = min(b0 + per, NN);
    int s = 0;
    for (int i = b0; i < b1; ++i) s += counts[i];
    part[t] = s; __syncthreads();
    for (int d = 1; d < 1024; d <<= 1) {
        int v = (t >= d) ? part[t-d] : 0;
        __syncthreads();
        part[t] += v;
        __syncthreads();
    }
    int run = (t == 0) ? 0 : part[t-1];
    for (int i = b0; i < b1; ++i) { row_ptr[i] = run; cursor[i] = run; run += counts[i]; }
    if (t == 0) row_ptr[NN] = EE;
}

// slim scatter: one packed {src, e} 8B random write per edge
__global__ void k_scatter(const int* __restrict__ ei, int* __restrict__ cursor,
                          int2* __restrict__ pair) {
    int e = blockIdx.x*256 + threadIdx.x;
    if (e < EE) {
        int d = ei[EE + e];
        int p = atomicAdd(&cursor[d], 1);
        pair[p] = make_int2(ei[e], e);
    }
}

// ---------------- layer 0 xl/xr via folded K=5 (fp16 out) ----------------
__global__ void k_xlxr0(const float* __restrict__ x, const float* __restrict__ Acat,
                        _Float16* __restrict__ xlxr16) {
    int n = blockIdx.x, j = threadIdx.x;
    float a0 = Acat[5*512 + j], a1 = Acat[5*512 + 256 + j];
#pragma unroll
    for (int k = 0; k < 5; ++k) {
        float xv = x[n*5 + k];
        a0 += xv * Acat[k*512 + j];
        a1 += xv * Acat[k*512 + 256 + j];
    }
    xlxr16[(size_t)n*512 + j] = (_Float16)a0;
    xlxr16[(size_t)n*512 + 256 + j] = (_Float16)a1;
}

// ---------------- fused GATv2 layer: low-VGPR, pair-indirect gathers, fused BN stats ----
// 4 nodes/block; wave w = head w. Depth-1 prefetch, Wpt B-fragments reloaded per tile (L1).
#define NPB 4

#define LOADT() { \
    int er = tl + srow; if (er >= el) er = el - 1; \
    const _Float16* sp = &xlxr16[(size_t)pairp[er].x*512 + wave*64 + scol]; \
    rx0 = *(const half8*)&sp[0]; \
    rx1 = *(const half8*)&sp[8]; \
    int arow = tl + l15; if (arow >= el) arow = el - 1; \
    const _Float16* ap = &attr16[(size_t)pairp[arow].y*64]; \
    ra0 = *(const half8*)&ap[l4*8]; \
    ra1 = *(const half8*)&ap[32 + l4*8]; \
    rxr = (float)xlxr16[(size_t)nl*512 + 256 + wave*64 + lane]; \
}

__global__ __launch_bounds__(256) void k_fused(const _Float16* __restrict__ attr16,
        const int2* __restrict__ pairp, const int* __restrict__ row_ptr,
        const _Float16* __restrict__ Wpt, const float* __restrict__ att,
        const _Float16* __restrict__ xlxr16, _Float16* __restrict__ gat16,
        float* __restrict__ stats) {
    int tid = threadIdx.x;
    int wave = tid >> 6, lane = tid & 63;
    int l15 = lane & 15, l4 = lane >> 4;
    int srow = lane >> 2, scol = (lane & 3) * 16;

    __shared__ __align__(16) _Float16 xls[4][16][72];   // wave-private single buffer

    // per-lane Wpt fragment base (fragments reloaded per tile from L1-resident 32KB table)
    const _Float16* bp = Wpt + (size_t)(wave*64 + l15)*64 + l4*8;
    float attv[4];
#pragma unroll
    for (int ct = 0; ct < 4; ++ct) attv[ct] = att[wave*64 + ct*16 + l15];

    int n0 = blockIdx.x*NPB;
    int nEnd = n0 + NPB; if (nEnd > NN) nEnd = NN;

    // zero-fill empty nodes; find first nonempty
    int nc = -1, tc = 0, ec = 0;
    for (int m = n0; m < nEnd; ++m) {
        int s = row_ptr[m], e = row_ptr[m+1];
        if (e <= s) gat16[(size_t)m*256 + wave*64 + lane] = (_Float16)0.f;
        else if (nc < 0) { nc = m; tc = s; ec = e; }
    }
    if (nc < 0) return;

    int nl = nc, tl = tc, el = ec;
    auto advIt = [&](int& n, int& t, int& e) -> bool {
        t += 16;
        if (t < e) return true;
        for (;;) {
            ++n;
            if (n >= nEnd) return false;
            int s = row_ptr[n]; e = row_ptr[n+1];
            if (e > s) { t = s; return true; }
        }
    };

    half8 rx0, rx1, ra0, ra1;
    float rxr;
    LOADT();
    bool haveL = advIt(nl, tl, el);

    float m_run = -3.0e38f, l_run = 0.f, out_acc = 0.f;
    float sAcc = 0.f, qAcc = 0.f;
    for (;;) {
        int nt = ec - tc; if (nt > 16) nt = 16;
        // stage current tile
        *(half8*)&xls[wave][srow][scol]     = rx0;
        *(half8*)&xls[wave][srow][scol + 8] = rx1;
        // MFMA with per-tile B-fragment reload (L1 hit)
        floatx4 acc[4];
#pragma unroll
        for (int ct = 0; ct < 4; ++ct) {
            half8 b0 = *(const half8*)(bp + ct*1024);
            half8 b1 = *(const half8*)(bp + ct*1024 + 32);
            floatx4 z = {};
            acc[ct] = __builtin_amdgcn_mfma_f32_16x16x32_f16(ra0, b0, z, 0, 0, 0);
            acc[ct] = __builtin_amdgcn_mfma_f32_16x16x32_f16(ra1, b1, acc[ct], 0, 0, 0);
        }
        // xr fragment via shuffle
        float xrf[4];
#pragma unroll
        for (int ct = 0; ct < 4; ++ct) xrf[ct] = __shfl(rxr, ct*16 + l15);
        // prefetch next tile (regs free after MFMA/shfl issue)
        if (haveL) { LOADT(); haveL = advIt(nl, tl, el); }
        // alpha combine (p[r] uniform within 16-lane group after reduce)
        float p[4];
#pragma unroll
        for (int r = 0; r < 4; ++r) {
            int eidx = l4*4 + r;
            float pv = 0.f;
#pragma unroll
            for (int ct = 0; ct < 4; ++ct) {
                float m = acc[ct][r] + (float)xls[wave][eidx][ct*16 + l15] + xrf[ct];
                float lr = fmaxf(m, 0.2f*m);
                pv += lr * attv[ct];
            }
            pv += __shfl_xor(pv, 1);
            pv += __shfl_xor(pv, 2);
            pv += __shfl_xor(pv, 4);
            pv += __shfl_xor(pv, 8);
            p[r] = (eidx < nt) ? pv : -3.0e38f;
        }
        // tile max: intra-lane over group's 4 edges, then cross-group
        float mt = fmaxf(fmaxf(p[0], p[1]), fmaxf(p[2], p[3]));
        mt = fmaxf(mt, __shfl_xor(mt, 16));
        mt = fmaxf(mt, __shfl_xor(mt, 32));
        float mnew = fmaxf(m_run, mt);
        float scale = __expf(m_run - mnew);
        out_acc *= scale; l_run *= scale;
        // 4 exps per lane (group-local), cross-group sum for denom
        float w4[4]; float wsum = 0.f;
#pragma unroll
        for (int r = 0; r < 4; ++r) { w4[r] = __expf(p[r] - mnew); wsum += w4[r]; }
        wsum += __shfl_xor(wsum, 16);
        wsum += __shfl_xor(wsum, 32);
        l_run += wsum;
        // accumulate: broadcast w (shfl) instead of recomputing exp
#pragma unroll
        for (int k = 0; k < 16; ++k) {
            float wk = __shfl(w4[k & 3], (k >> 2) << 4);
            out_acc += wk * (float)xls[wave][k][lane];
        }
        m_run = mnew;
        if (tc + 16 >= ec) {
            _Float16 h = (_Float16)(out_acc / l_run);
            gat16[(size_t)nc*256 + wave*64 + lane] = h;
            float hv = (float)h;
            sAcc += hv; qAcc += hv*hv;
            m_run = -3.0e38f; l_run = 0.f; out_acc = 0.f;
        }
        if (!advIt(nc, tc, ec)) break;
    }
    // fused BN stats: 16-sharded per-col partial sums
    int shard = blockIdx.x & 15;
    atomicAdd(&stats[shard*512 + wave*64 + lane], sAcc);
    atomicAdd(&stats[shard*512 + 256 + wave*64 + lane], qAcc);
}

// ---------------- fp16 MFMA GEMM with fused BN-finalize + BN+ReLU on A ----------------
template<bool RELU, typename OT>
__global__ __launch_bounds__(256) void k_gemm(const _Float16* __restrict__ A,
                       const float* __restrict__ stats,
                       const float* __restrict__ gamma, const float* __restrict__ beta,
                       const _Float16* __restrict__ Bt,
                       const float* __restrict__ bias, OT* __restrict__ C,
                       int M, int ldc) {
    __shared__ __align__(16) _Float16 As[128][72];
    __shared__ __align__(16) _Float16 Bs[64][72];
    __shared__ float ssS[256], ssB[256];
    int tid = threadIdx.x;
    int wave = tid >> 6, lane = tid & 63;
    int l15 = lane & 15, l4 = lane >> 4;
    int row0 = blockIdx.x*128, n0 = blockIdx.y*64;
    // BN finalize (per block, from 16-sharded stats; L2-hot)
    {
        int j = tid;
        if (j < 256) {
            float s = 0.f, q = 0.f;
#pragma unroll
            for (int sh = 0; sh < 16; ++sh) {
                s += stats[sh*512 + j];
                q += stats[sh*512 + 256 + j];
            }
            float mean = s * (1.0f/NN);
            float var  = q * (1.0f/NN) - mean*mean;
            float sc = rsqrtf(var + 1e-5f) * gamma[j];
            ssS[j] = sc;
            ssB[j] = beta[j] - mean*sc;
        }
    }
    __syncthreads();
    floatx4 acc[2][4] = {};
    for (int k0 = 0; k0 < 256; k0 += 64) {
#pragma unroll
        for (int q = 0; q < 4; ++q) {
            int c = tid + q*256;
            int r = c >> 3, kc = (c & 7)*8;
            int gr = row0 + r; if (gr >= M) gr = M - 1;
            half8 g = *(const half8*)&A[(size_t)gr*256 + k0 + kc];
            _Float16 tmp[8];
#pragma unroll
            for (int i = 0; i < 8; ++i) {
                int colk = k0 + kc + i;
                float v = (float)g[i]*ssS[colk] + ssB[colk];
                tmp[i] = (_Float16)fmaxf(v, 0.f);
            }
            *(half8*)&As[r][kc] = *(half8*)tmp;
        }
#pragma unroll
        for (int q = 0; q < 2; ++q) {
            int c = tid + q*256;
            int r = c >> 3, kc = (c & 7)*8;
            *(half8*)&Bs[r][kc] = *(const half8*)&Bt[(size_t)(n0 + r)*256 + k0 + kc];
        }
        __syncthreads();
#pragma unroll
        for (int ks = 0; ks < 64; ks += 32) {
            half8 a0 = *(const half8*)&As[wave*32 + l15][ks + l4*8];
            half8 a1 = *(const half8*)&As[wave*32 + 16 + l15][ks + l4*8];
#pragma unroll
            for (int nb = 0; nb < 4; ++nb) {
                half8 b = *(const half8*)&Bs[nb*16 + l15][ks + l4*8];
                acc[0][nb] = __builtin_amdgcn_mfma_f32_16x16x32_f16(a0, b, acc[0][nb], 0, 0, 0);
                acc[1][nb] = __builtin_amdgcn_mfma_f32_16x16x32_f16(a1, b, acc[1][nb], 0, 0, 0);
            }
        }
        __syncthreads();
    }
#pragma unroll
    for (int m = 0; m < 2; ++m)
#pragma unroll
    for (int nb = 0; nb < 4; ++nb) {
        int col = n0 + nb*16 + l15;
        float bv = bias[col];
#pragma unroll
        for (int r = 0; r < 4; ++r) {
            int grow = row0 + wave*32 + m*16 + l4*4 + r;
            if (grow < M) {
                float v = acc[m][nb][r] + bv;
                if (RELU) v = fmaxf(v, 0.f);
                C[(size_t)grow*ldc + col] = (OT)v;
            }
        }
    }
}

// ---------------- pooling (batch sorted -> contiguous ranges, no atomics) ----------------
__global__ void k_pool2(const float* __restrict__ mo, const int* __restrict__ batch,
                        float* __restrict__ pooledDiv) {
    int b = blockIdx.x;
    int j = threadIdx.x & 63, rg = threadIdx.x >> 6;
    int lo = 0, hi = NN;
    while (lo < hi) { int mid = (lo + hi) >> 1; if (batch[mid] < b) lo = mid + 1; else hi = mid; }
    int s = lo;
    lo = 0; hi = NN;
    while (lo < hi) { int mid = (lo + hi) >> 1; if (batch[mid] < b + 1) lo = mid + 1; else hi = mid; }
    int e = lo;
    float acc = 0.f;
    for (int r = s + rg; r < e; r += 4) acc += mo[(size_t)r*64 + j];
    __shared__ float red[256];
    red[threadIdx.x] = acc;
    __syncthreads();
    if (rg == 0) {
        float v = red[j] + red[64 + j] + red[128 + j] + red[192 + j];
        pooledDiv[b*64 + j] = v / fmaxf((float)(e - s), 1.f);
    }
}

__global__ void k_final(const float* __restrict__ pooledDiv,
                        const float* __restrict__ outW, const float* __restrict__ outb,
                        float* __restrict__ out) {
    int t = threadIdx.x;
    if (t >= 320) return;
    int b = t / 5, c = t % 5;
    float acc = outb[c];
    for (int k = 0; k < 64; ++k) acc += pooledDiv[b*64 + k] * outW[k*5 + c];
    out[t] = acc;
}

extern "C" void kernel_launch(void* const* d_in, const int* in_sizes, int n_in,
                              void* d_out, int out_size, void* d_ws, size_t ws_size,
                              hipStream_t stream) {
    const float* x      = (const float*)d_in[0];
    const int*   ei     = (const int*)d_in[1];
    const float* attr   = (const float*)d_in[2];
    const int*   batch  = (const int*)d_in[3];
    const float* node_W = (const float*)d_in[4];
    const float* node_b = (const float*)d_in[5];
    const float* edge_W = (const float*)d_in[6];
    const float* edge_b = (const float*)d_in[7];
    const float* Wl[2]   = {(const float*)d_in[8],  (const float*)d_in[17]};
    const float* bl[2]   = {(const float*)d_in[9],  (const float*)d_in[18]};
    const float* Wr[2]   = {(const float*)d_in[10], (const float*)d_in[19]};
    const float* br[2]   = {(const float*)d_in[11], (const float*)d_in[20]};
    const float* We[2]   = {(const float*)d_in[12], (const float*)d_in[21]};
    const float* att[2]  = {(const float*)d_in[13], (const float*)d_in[22]};
    const float* gamma[2]= {(const float*)d_in[15], (const float*)d_in[24]};
    const float* beta[2] = {(const float*)d_in[16], (const float*)d_in[25]};
    const float* mlp_W = (const float*)d_in[26];
    const float* mlp_b = (const float*)d_in[27];
    const float* out_W = (const float*)d_in[28];
    const float* out_b = (const float*)d_in[29];
    float* out = (float*)d_out;

    char* p = (char*)d_ws;
    size_t off = 0;
    auto carve = [&](size_t bytes) -> void* {
        void* r = p + off;
        off = (off + bytes + 255) & ~(size_t)255;
        return r;
    };
    _Float16* Wpt0   = (_Float16*)carve(256*64*2);
    _Float16* Wpt1   = (_Float16*)carve(256*64*2);
    float*    Acat   = (float*)carve(6*512*4);
    _Float16* WlWr1t = (_Float16*)carve(512*256*2);
    float*    blr1   = (float*)carve(512*4);
    _Float16* mlpWt  = (_Float16*)carve(64*256*2);
    _Float16* xlxr16 = (_Float16*)carve((size_t)NN*512*2);
    _Float16* gat16  = (_Float16*)carve((size_t)NN*256*2);
    float*    mlo    = (float*)carve((size_t)NN*64*4);
    _Float16* attr16 = (_Float16*)carve((size_t)EE*64*2);
    int*      row_ptr= (int*)carve((NN+1)*4);
    int2*     pairA  = (int2*)carve((size_t)EE*8);
    int*      cursor = (int*)carve(NN*4);
    float*    pooledDiv = (float*)carve(BB*64*4);
    int*      counts = (int*)carve(NN*4);
    float*    stats  = (float*)carve(2*16*512*4);   // 2 layers x 16 shards x 512
    if (off > ws_size) return;  // workspace too small: bail

    k_prep_edgeW<<<dim3(64,2), 256, 0, stream>>>(edge_W, edge_b, We[0], We[1], Wpt0, Wpt1, counts);
    k_prep_acat<<<6, 512, 0, stream>>>(node_W, node_b, Wl[0], bl[0], Wr[0], br[0], Acat);
    k_prep_t16<<<576, 256, 0, stream>>>(Wl[1], bl[1], Wr[1], br[1], mlp_W, WlWr1t, blr1, mlpWt, stats);
    k_conv_hist<<<EE/4, 256, 0, stream>>>(ei, attr, attr16, counts);
    k_scan<<<1, 1024, 0, stream>>>(counts, row_ptr, cursor);
    k_scatter<<<(EE+255)/256, 256, 0, stream>>>(ei, cursor, pairA);
    k_xlxr0<<<NN, 256, 0, stream>>>(x, Acat, xlxr16);

    for (int L = 0; L < 2; ++L) {
        k_fused<<<(NN + NPB - 1)/NPB, 256, 0, stream>>>(attr16, pairA, row_ptr,
                 L ? Wpt1 : Wpt0, att[L], xlxr16, gat16, stats + L*8192);
        if (L == 0)
            k_gemm<false, _Float16><<<dim3(157, 8), 256, 0, stream>>>(gat16, stats, gamma[0], beta[0],
                     WlWr1t, blr1, xlxr16, NN, 512);
        else
            k_gemm<true, float><<<dim3(157, 1), 256, 0, stream>>>(gat16, stats + 8192, gamma[1], beta[1],
                     mlpWt, mlp_b, mlo, NN, 64);
    }
    k_pool2<<<BB, 256, 0, stream>>>(mlo, batch, pooledDiv);
    k_final<<<1, 320, 0, stream>>>(pooledDiv, out_W, out_b, out);
}